// Round 1
// 250.424 us; speedup vs baseline: 1.0156x; 1.0156x over previous
//
#include <hip/hip_runtime.h>

#define B_DIM 2048
#define IN_DIM 1024
#define OUT_DIM 1024
#define K_KNOTS 20
#define KR (IN_DIM * K_KNOTS)   // 20480 reduction dim
#define OUT_ELEMS (B_DIM * OUT_DIM)

// ---- old 128x128 kernel geometry (kept as mid-workspace fallback) ----
#define TM 128
#define TN 128
#define BK 128
#define KSPLIT 4
#define MT_TILES (B_DIM / TM)   // 16
#define NT_TILES (OUT_DIM / TN) // 8
#define GEMM_BLOCKS (MT_TILES * NT_TILES * KSPLIT)  // 512
#define LDS_AS0 0
#define LDS_AS1 8192
#define LDS_BS0 16384
#define LDS_BS1 24576

// ---- prep sizing ----
#define NB_QUADS (B_DIM * IN_DIM * 5)             // 10,485,760 threads (4 knots each)
#define NB_BASIS_BLK (NB_QUADS / 256)             // 40960 blocks
#define NW4 (OUT_DIM * KR / 8)                    // 2,621,440 uint4 outputs
#define NB_W_BLK (NW4 / 256)                      // 10240 blocks

typedef __bf16 bf16x8 __attribute__((ext_vector_type(8)));
typedef float  f32x4  __attribute__((ext_vector_type(4)));

#define MFMA16(a, b, c) __builtin_amdgcn_mfma_f32_16x16x32_bf16(a, b, c, 0, 0, 0)

__device__ __forceinline__ unsigned short f2bf(float f) {
    unsigned int u = __float_as_uint(f);
    unsigned int r = u + 0x7fffu + ((u >> 16) & 1u);   // RNE; no NaN inputs here
    return (unsigned short)(r >> 16);
}

__device__ __forceinline__ unsigned int pack2(float lo, float hi) {
    return (unsigned int)f2bf(lo) | ((unsigned int)f2bf(hi) << 16);
}

__device__ __forceinline__ void async_load16(const void* g, void* l) {
    __builtin_amdgcn_global_load_lds(
        (const __attribute__((address_space(1))) void*)g,
        (__attribute__((address_space(3))) void*)l,
        16, 0, 0);
}

// ---------------- zero the output (atomic fallback path only) ----------------
__global__ void zero_out_kernel(float* out) {
    int idx = (blockIdx.x * 256 + threadIdx.x) * 4;
    float4 z = {0.f, 0.f, 0.f, 0.f};
    *(float4*)(out + idx) = z;
}

// ------- merged prep: basis bf16 (B,IN*K) + W fp32->bf16, one dispatch -------
__global__ void __launch_bounds__(256) prep_kernel(
        const float* __restrict__ x,
        const float4* __restrict__ Wsrc,
        const float* __restrict__ knots,
        uint2* __restrict__ basis_out,
        uint4* __restrict__ w_out) {
    if (blockIdx.x < NB_BASIS_BLK) {
        unsigned int n = blockIdx.x * 256 + threadIdx.x;   // quad index
        unsigned int q  = n % 5u;                          // which knot-quad
        unsigned int bi = n / 5u;                          // b*1024 + i
        float t0 = knots[0];
        float h  = knots[1] - t0;
        float invh = 1.0f / h;
        float xv = x[bi];
        float k0 = (float)(4 * q);
        float v[4];
#pragma unroll
        for (int j = 0; j < 4; ++j) {
            float t = __builtin_fmaf(k0 + (float)j, h, t0);
            float d = (xv - t) * invh;
            v[j] = __expf(-0.5f * d * d);
        }
        uint2 o;
        o.x = pack2(v[0], v[1]);
        o.y = pack2(v[2], v[3]);
        basis_out[n] = o;
    } else {
        unsigned int t = (blockIdx.x - NB_BASIS_BLK) * 256 + threadIdx.x;
        float4 a = Wsrc[2 * t];
        float4 b = Wsrc[2 * t + 1];
        uint4 o;
        o.x = pack2(a.x, a.y);
        o.y = pack2(a.z, a.w);
        o.z = pack2(b.x, b.y);
        o.w = pack2(b.z, b.w);
        w_out[t] = o;
    }
}

// ============================================================================
// NEW: 256x256 / BK=64 / 8-wave 8-phase counted-vmcnt GEMM (m201 structure).
//
// LDS (shorts): A slot s, half h at ((s*2+h)*8192); B at 32768 + same.
// Slot s = ktile&1; half h = tile-row>>7. Row stride 64 shorts; 16B col-slot
// swizzle (cs ^ (row&7)) -- the verified conflict-free pattern from R8/R10.
// Staging: global_load_lds writes LDS linearly (base + lane*16); the source
// global col is pre-swizzled: ((lane&7) ^ (lane>>3)) * 8  (rule-21 pattern).
//
// Schedule per K-tile group G_t (slot s=t&1), 4 phases:
//  Ph1: read A-frags i0..3 (8 ds) + B-frags j0..1 (4 ds); stage B(t+1).h1
//  Ph2: read B-frags j2..3 (4 ds);                        stage A(t+1).h1
//  Ph3: read A-frags i4..7 (8 ds);                        stage B(t+2).h0
//  Ph4: (no reads, reuse regs);                           stage A(t+2).h0
//  each phase: barrier; lgkmcnt(0); setprio(1); 16 MFMA; setprio(0); barrier
//  group end: vmcnt(4)  (the 4 newest loads = tile t+2 halves stay in flight;
//  tile t+1 is fully confirmed).  Overwrite safety: every stage targets a
//  region whose last ds_read completed before the preceding barrier (reads
//  are lgkmcnt-waited before each phase's MFMAs, hence before the barrier).
//  Tail: t >= NTILES-2 uses vmcnt(0) once to confirm the final tile.
// ============================================================================
#define AOFF(s, h) (((s) * 2 + (h)) * 8192)
#define BOFF(s, h) (32768 + ((s) * 2 + (h)) * 8192)

template <int KS, bool ATOMIC>
__global__ void __launch_bounds__(512, 2)
kan_gemm8(const unsigned short* __restrict__ Ab,   // (2048, 20480) bf16 row-major
          const unsigned short* __restrict__ Bb,   // (1024, 20480) bf16 row-major
          float* __restrict__ out) {
    __shared__ __align__(16) unsigned short lds[65536];   // 128 KiB

    constexpr int KPBk   = KR / KS;          // 2560
    constexpr int NTILES = KPBk / 64;        // 40

    const int id  = blockIdx.x;
    const int z   = id & 7;                  // K-split slice -> one per XCD
    const int ord = id >> 3;                 // 0..31
    const int mt  = ord & 7;
    const int nt  = ord >> 3;                // 0..3
    const int m0  = mt * 256;
    const int n0  = nt * 256;
    const int k0  = z * KPBk;

    const int tid  = threadIdx.x;
    const int wave = tid >> 6;               // 0..7
    const int lane = tid & 63;
    const int wm   = wave >> 2;              // 0..1 -> wave owns 128 M-rows
    const int wn   = wave & 3;               // 0..3 -> wave owns 64 N-cols

    const int srow8 = lane >> 3;                    // staging row within 8-row chunk
    const int scol  = ((lane & 7) ^ srow8) * 8;     // pre-swizzled global col

    // stage one 128x64 half-tile: wave covers rows grow+wave*16+{0..7,8..15}
    auto stage = [&](const unsigned short* __restrict__ src, int grow, int kb, int lbase) {
        const unsigned short* g = src + (size_t)(grow + wave * 16 + srow8) * KR + kb + scol;
        async_load16(g,                  &lds[lbase + wave * 1024]);
        async_load16(g + (size_t)8 * KR, &lds[lbase + wave * 1024 + 512]);
    };

    f32x4 acc[8][4];
#pragma unroll
    for (int i = 0; i < 8; ++i)
#pragma unroll
        for (int j = 0; j < 4; ++j) acc[i][j] = (f32x4){0.f, 0.f, 0.f, 0.f};

    const int q   = lane >> 4;
    const int r15 = lane & 15;
    const int r7  = lane & 7;
    const int c0  = (q ^ r7) * 8;            // swizzled 16B slot, kstep 0
    const int c1  = ((4 + q) ^ r7) * 8;      // swizzled 16B slot, kstep 1

    // prologue: all of tile 0, then first halves of tile 1 (order matters!)
    stage(Ab, m0,       k0,      AOFF(0, 0));
    stage(Ab, m0 + 128, k0,      AOFF(0, 1));
    stage(Bb, n0,       k0,      BOFF(0, 0));
    stage(Bb, n0 + 128, k0,      BOFF(0, 1));
    stage(Bb, n0,       k0 + 64, BOFF(1, 0));
    stage(Ab, m0,       k0 + 64, AOFF(1, 0));
    asm volatile("s_waitcnt vmcnt(4)" ::: "memory");   // tile 0 confirmed
    __builtin_amdgcn_s_barrier();

#pragma unroll 2
    for (int t = 0; t < NTILES; ++t) {
        const int s   = t & 1;
        const int aB  = s * 16384 + (wm * 128 + r15) * 64;
        const int bB  = 32768 + s * 16384 + (wn * 64 + r15) * 64;
        const int kb1 = k0 + (t + 1) * 64;
        const int kb2 = k0 + (t + 2) * 64;
        bf16x8 aR[4][2], bR[4][2];

        // ---------------- phase 1: (i0..3) x (j0..1) ----------------
#pragma unroll
        for (int i = 0; i < 4; ++i) {
            aR[i][0] = *(const bf16x8*)&lds[aB + i * 1024 + c0];
            aR[i][1] = *(const bf16x8*)&lds[aB + i * 1024 + c1];
        }
#pragma unroll
        for (int j = 0; j < 2; ++j) {
            bR[j][0] = *(const bf16x8*)&lds[bB + j * 1024 + c0];
            bR[j][1] = *(const bf16x8*)&lds[bB + j * 1024 + c1];
        }
        if (t + 1 < NTILES) stage(Bb, n0 + 128, kb1, BOFF(s ^ 1, 1));
        __builtin_amdgcn_s_barrier();
        asm volatile("s_waitcnt lgkmcnt(0)" ::: "memory");
        __builtin_amdgcn_sched_barrier(0);
        __builtin_amdgcn_s_setprio(1);
#pragma unroll
        for (int i = 0; i < 4; ++i)
#pragma unroll
            for (int j = 0; j < 2; ++j) {
                acc[i][j] = MFMA16(aR[i][0], bR[j][0], acc[i][j]);
                acc[i][j] = MFMA16(aR[i][1], bR[j][1], acc[i][j]);
            }
        __builtin_amdgcn_s_setprio(0);
        __builtin_amdgcn_s_barrier();

        // ---------------- phase 2: (i0..3) x (j2..3) ----------------
#pragma unroll
        for (int j = 2; j < 4; ++j) {
            bR[j][0] = *(const bf16x8*)&lds[bB + j * 1024 + c0];
            bR[j][1] = *(const bf16x8*)&lds[bB + j * 1024 + c1];
        }
        if (t + 1 < NTILES) stage(Ab, m0 + 128, kb1, AOFF(s ^ 1, 1));
        __builtin_amdgcn_s_barrier();
        asm volatile("s_waitcnt lgkmcnt(0)" ::: "memory");
        __builtin_amdgcn_sched_barrier(0);
        __builtin_amdgcn_s_setprio(1);
#pragma unroll
        for (int i = 0; i < 4; ++i)
#pragma unroll
            for (int j = 2; j < 4; ++j) {
                acc[i][j] = MFMA16(aR[i][0], bR[j][0], acc[i][j]);
                acc[i][j] = MFMA16(aR[i][1], bR[j][1], acc[i][j]);
            }
        __builtin_amdgcn_s_setprio(0);
        __builtin_amdgcn_s_barrier();

        // ---------------- phase 3: (i4..7) x (j2..3) ----------------
#pragma unroll
        for (int i = 0; i < 4; ++i) {
            aR[i][0] = *(const bf16x8*)&lds[aB + (4 + i) * 1024 + c0];
            aR[i][1] = *(const bf16x8*)&lds[aB + (4 + i) * 1024 + c1];
        }
        if (t + 2 < NTILES) stage(Bb, n0, kb2, BOFF(s, 0));
        __builtin_amdgcn_s_barrier();
        asm volatile("s_waitcnt lgkmcnt(0)" ::: "memory");
        __builtin_amdgcn_sched_barrier(0);
        __builtin_amdgcn_s_setprio(1);
#pragma unroll
        for (int i = 0; i < 4; ++i)
#pragma unroll
            for (int j = 2; j < 4; ++j) {
                acc[4 + i][j] = MFMA16(aR[i][0], bR[j][0], acc[4 + i][j]);
                acc[4 + i][j] = MFMA16(aR[i][1], bR[j][1], acc[4 + i][j]);
            }
        __builtin_amdgcn_s_setprio(0);
        __builtin_amdgcn_s_barrier();

        // ---------------- phase 4: (i4..7) x (j0..1), reuse regs ----------------
        if (t + 2 < NTILES) stage(Ab, m0, kb2, AOFF(s, 0));
        __builtin_amdgcn_s_setprio(1);
#pragma unroll
        for (int i = 0; i < 4; ++i)
#pragma unroll
            for (int j = 0; j < 2; ++j) {
                acc[4 + i][j] = MFMA16(aR[i][0], bR[j][0], acc[4 + i][j]);
                acc[4 + i][j] = MFMA16(aR[i][1], bR[j][1], acc[4 + i][j]);
            }
        __builtin_amdgcn_s_setprio(0);
        if (t < NTILES - 2) asm volatile("s_waitcnt vmcnt(4)" ::: "memory");
        else                asm volatile("s_waitcnt vmcnt(0)" ::: "memory");
        __builtin_amdgcn_s_barrier();
    }

    // epilogue: C/D layout col=lane&15, row=(lane>>4)*4+reg
    float* dst = ATOMIC ? out : out + (size_t)z * OUT_ELEMS;
#pragma unroll
    for (int i = 0; i < 8; ++i)
#pragma unroll
        for (int j = 0; j < 4; ++j)
#pragma unroll
            for (int r = 0; r < 4; ++r) {
                const int row = m0 + wm * 128 + i * 16 + q * 4 + r;
                const int c   = n0 + wn * 64  + j * 16 + r15;
                if (ATOMIC)
                    atomicAdd(&dst[(size_t)row * OUT_DIM + c], acc[i][j][r]);
                else
                    dst[(size_t)row * OUT_DIM + c] = acc[i][j][r];
            }
}

// ---------------- OLD bf16 MFMA GEMM (mid-workspace fallback, verified) ------
template <int KS, bool ATOMIC>
__global__ void __launch_bounds__(256)
kan_gemm(const unsigned short* __restrict__ Ab,
         const unsigned short* __restrict__ Bb,
         float* __restrict__ out) {
    __shared__ __align__(16) unsigned short lds[32768];   // 64 KB

    const int KPBk = KR / KS;
    const int id   = blockIdx.x;
    const int xcd  = id & 7;
    const int ord  = id >> 3;
    const int mt   = xcd * 2 + (ord & 1);
    const int nt   = (ord >> 1) & (NT_TILES - 1);
    const int z    = ord >> 4;
    const int m0 = mt * TM;
    const int n0 = nt * TN;
    const int k0 = z * KPBk;

    const int tid  = threadIdx.x;
    const int wave = tid >> 6;
    const int lane = tid & 63;
    const int wm = wave & 1;
    const int wn = wave >> 1;

    const int srow = lane >> 3;
    const int scol = ((lane & 7) ^ srow) * 8;

    f32x4 acc[4][4];
#pragma unroll
    for (int i = 0; i < 4; ++i)
#pragma unroll
        for (int j = 0; j < 4; ++j) acc[i][j] = (f32x4){0.f, 0.f, 0.f, 0.f};

    for (int kt = 0; kt < KPBk; kt += BK) {
        const int kb = k0 + kt;
        __syncthreads();
#pragma unroll
        for (int c = 0; c < 4; ++c) {
            const int chunk = wave * 4 + c;
            const int r = chunk * 8 + srow;
            const unsigned short* arow = Ab + (size_t)(m0 + r) * KR + kb + scol;
            const unsigned short* brow = Bb + (size_t)(n0 + r) * KR + kb + scol;
            unsigned short* slot = &lds[chunk * 512];
            async_load16(arow,      slot + LDS_AS0);
            async_load16(arow + 64, slot + LDS_AS1);
            async_load16(brow,      slot + LDS_BS0);
            async_load16(brow + 64, slot + LDS_BS1);
        }
        __syncthreads();

        const int quad = lane >> 4;
        const int r15  = lane & 15;
        const int r7   = lane & 7;
#pragma unroll
        for (int s = 0; s < 4; ++s) {
            const int abase = (s >> 1) ? LDS_AS1 : LDS_AS0;
            const int bbase = (s >> 1) ? LDS_BS1 : LDS_BS0;
            const int cg = (s & 1) * 4 + quad;
            const int xo = (cg ^ r7) * 8;
            bf16x8 af[4], bfv[4];
#pragma unroll
            for (int i = 0; i < 4; ++i) {
                af[i]  = *(const bf16x8*)&lds[abase + (wm * 64 + i * 16 + r15) * 64 + xo];
                bfv[i] = *(const bf16x8*)&lds[bbase + (wn * 64 + i * 16 + r15) * 64 + xo];
            }
#pragma unroll
            for (int i = 0; i < 4; ++i)
#pragma unroll
                for (int j = 0; j < 4; ++j)
                    acc[i][j] = MFMA16(af[i], bfv[j], acc[i][j]);
        }
    }

    float* dst = ATOMIC ? out : out + (size_t)z * OUT_ELEMS;
    const int quad = lane >> 4;
    const int col  = lane & 15;
#pragma unroll
    for (int i = 0; i < 4; ++i)
#pragma unroll
        for (int j = 0; j < 4; ++j)
#pragma unroll
            for (int r = 0; r < 4; ++r) {
                const int row = m0 + wm * 64 + i * 16 + quad * 4 + r;
                const int c   = n0 + wn * 64 + j * 16 + col;
                if (ATOMIC)
                    atomicAdd(&dst[(size_t)row * OUT_DIM + c], acc[i][j][r]);
                else
                    dst[(size_t)row * OUT_DIM + c] = acc[i][j][r];
            }
}

// ---------------- reduce KS partial slices -> out ----------------------------
template <int KS>
__global__ void kan_reduce(const float* __restrict__ part, float* __restrict__ out) {
    const int idx = (blockIdx.x * 256 + threadIdx.x) * 4;
    f32x4 s = *(const f32x4*)(part + idx);
#pragma unroll
    for (int z = 1; z < KS; ++z)
        s += *(const f32x4*)(part + (size_t)z * OUT_ELEMS + idx);
    *(f32x4*)(out + idx) = s;
}

// ---------------- fallback (ws too small): correctness-only fp32 -------------
__global__ void kan_fallback(const float* __restrict__ x,
                             const float* __restrict__ W,
                             const float* __restrict__ knots,
                             float* __restrict__ out) {
    __shared__ float basis[256 * K_KNOTS];
    const int b = blockIdx.x;
    const int o = blockIdx.y * blockDim.x + threadIdx.x;
    const float invh = 1.0f / (knots[1] - knots[0]);
    const float* w = W + (size_t)o * KR;
    float sum = 0.f;
    for (int i0 = 0; i0 < IN_DIM; i0 += 256) {
        __syncthreads();
        for (int idx = threadIdx.x; idx < 256 * K_KNOTS; idx += blockDim.x) {
            const int i = i0 + idx / K_KNOTS;
            const int k = idx % K_KNOTS;
            const float d = (x[(size_t)b * IN_DIM + i] - knots[k]) * invh;
            basis[idx] = __expf(-0.5f * d * d);
        }
        __syncthreads();
        for (int r = 0; r < 256 * K_KNOTS; ++r)
            sum += basis[r] * w[(size_t)i0 * K_KNOTS + r];
    }
    out[(size_t)b * OUT_DIM + o] = sum;
}

extern "C" void kernel_launch(void* const* d_in, const int* in_sizes, int n_in,
                              void* d_out, int out_size, void* d_ws, size_t ws_size,
                              hipStream_t stream) {
    const float* x     = (const float*)d_in[0];
    const float* W     = (const float*)d_in[1];
    const float* knots = (const float*)d_in[2];
    float* out = (float*)d_out;

    const size_t basis_bytes = (size_t)B_DIM * KR * 2;              // 80 MiB
    const size_t wb_bytes    = (size_t)OUT_DIM * KR * 2;            // 40 MiB
    const size_t part8_bytes = (size_t)8 * OUT_ELEMS * 4;           // 64 MiB
    const size_t part4_bytes = (size_t)4 * OUT_ELEMS * 4;           // 32 MiB

    unsigned short* Ab = (unsigned short*)d_ws;
    unsigned short* Bb = (unsigned short*)((char*)d_ws + basis_bytes);
    float* part = (float*)((char*)d_ws + basis_bytes + wb_bytes);

    if (ws_size >= basis_bytes + wb_bytes + part8_bytes) {
        // main path: 8-phase 256^2 GEMM, KSPLIT=8 (256 blocks = 1/CU)
        prep_kernel<<<dim3(NB_BASIS_BLK + NB_W_BLK), dim3(256), 0, stream>>>(
            x, (const float4*)W, knots, (uint2*)Ab, (uint4*)Bb);
        kan_gemm8<8, false><<<dim3(256), dim3(512), 0, stream>>>(Ab, Bb, part);
        kan_reduce<8><<<dim3(OUT_ELEMS / (256 * 4)), dim3(256), 0, stream>>>(part, out);
    } else if (ws_size >= basis_bytes + wb_bytes + part4_bytes) {
        // previous verified path (128^2, KSPLIT=4)
        prep_kernel<<<dim3(NB_BASIS_BLK + NB_W_BLK), dim3(256), 0, stream>>>(
            x, (const float4*)W, knots, (uint2*)Ab, (uint4*)Bb);
        kan_gemm<4, false><<<dim3(GEMM_BLOCKS), dim3(256), 0, stream>>>(Ab, Bb, part);
        kan_reduce<4><<<dim3(OUT_ELEMS / (256 * 4)), dim3(256), 0, stream>>>(part, out);
    } else if (ws_size >= basis_bytes + wb_bytes) {
        zero_out_kernel<<<dim3(OUT_ELEMS / (256 * 4)), dim3(256), 0, stream>>>(out);
        prep_kernel<<<dim3(NB_BASIS_BLK + NB_W_BLK), dim3(256), 0, stream>>>(
            x, (const float4*)W, knots, (uint2*)Ab, (uint4*)Bb);
        kan_gemm8<8, true><<<dim3(256), dim3(512), 0, stream>>>(Ab, Bb, out);
    } else {
        kan_fallback<<<dim3(B_DIM, OUT_DIM / 256), dim3(256), 0, stream>>>(x, W, knots, out);
    }
}